// Round 17
// baseline (354.941 us; speedup 1.0000x reference)
//
#include <hip/hip_runtime.h>
#include <hip/hip_bf16.h>

typedef __bf16 bf16_t;
typedef __bf16 bf16x8 __attribute__((ext_vector_type(8)));
typedef float  f32x4  __attribute__((ext_vector_type(4)));

#define MFMA16(a, b, c) __builtin_amdgcn_mfma_f32_16x16x32_bf16((a), (b), (c), 0, 0, 0)

#define ROWS 48   // 48-row tile; 3 LDS tiles = 76.9KB -> 2 blocks/CU (154 <= 160KB)

// Gray-code bank swizzle for [rows][256] bf16 LDS tiles (row stride 512B).
__device__ __forceinline__ int gray(int row) { return (row ^ (row >> 1)) & 7; }
__device__ __forceinline__ int swz256(int row, int col) {
    return row * 256 + ((((col >> 3) ^ gray(row)) << 3) | (col & 7));
}

__device__ __forceinline__ bf16x8 cvt8(float4 a, float4 b) {
    bf16x8 o;
    o[0] = (bf16_t)a.x; o[1] = (bf16_t)a.y; o[2] = (bf16_t)a.z; o[3] = (bf16_t)a.w;
    o[4] = (bf16_t)b.x; o[5] = (bf16_t)b.y; o[6] = (bf16_t)b.z; o[7] = (bf16_t)b.w;
    return o;
}

__device__ __forceinline__ unsigned enc_max(float x) {
    unsigned b = __float_as_uint(x);
    return (b & 0x80000000u) ? ~b : (b | 0x80000000u);
}
__device__ __forceinline__ float dec_max(unsigned e) {
    if (e == 0u) return 0.0f;
    return (e & 0x80000000u) ? __uint_as_float(e ^ 0x80000000u) : __uint_as_float(~e);
}

// ---- PAIRED per-wave GEMM: one A-stream feeds TWO weight streams ----
// [48,256](LDS, swizzled) @ {WkA, WkB}: A-fragments loaded once, 4 MFMAs each.
// Live regs: acc 48 + a 24 + b 16 + addr ~12 = ~100 <= 128 cap (4 waves/SIMD).
__device__ __forceinline__ void gemm256_pair(const bf16_t* __restrict__ As,
                                             const bf16_t* __restrict__ WkA,
                                             const bf16_t* __restrict__ WkB,
                                             f32x4 accA[3][2], f32x4 accB[3][2],
                                             int w, int l) {
    const int l15 = l & 15, hi = l >> 4;
#pragma unroll
    for (int mt = 0; mt < 3; ++mt)
#pragma unroll
        for (int j = 0; j < 2; ++j) {
            accA[mt][j] = (f32x4){0.f, 0.f, 0.f, 0.f};
            accB[mt][j] = (f32x4){0.f, 0.f, 0.f, 0.f};
        }
    const bf16_t* wbA = WkA + ((size_t)hi * 256 + w * 32 + l15) * 8;
    const bf16_t* wbB = WkB + ((size_t)hi * 256 + w * 32 + l15) * 8;

    bf16x8 bA0[2], bA1[2], bB0[2], bB1[2];
    bf16x8 a[2][3];
    bA0[0] = *(const bf16x8*)(wbA);
    bA1[0] = *(const bf16x8*)(wbA + 128);
    bB0[0] = *(const bf16x8*)(wbB);
    bB1[0] = *(const bf16x8*)(wbB + 128);
#pragma unroll
    for (int mt = 0; mt < 3; ++mt) {
        const int row = mt * 16 + l15;
        a[0][mt] = *(const bf16x8*)(As + row * 256 + (hi ^ gray(row)) * 8);
    }
#pragma unroll
    for (int kt = 0; kt < 8; ++kt) {
        const int cur = kt & 1, nxt = cur ^ 1;
        if (kt + 1 < 8) {
            bA0[nxt] = *(const bf16x8*)(wbA + (kt + 1) * 8192);
            bA1[nxt] = *(const bf16x8*)(wbA + (kt + 1) * 8192 + 128);
            bB0[nxt] = *(const bf16x8*)(wbB + (kt + 1) * 8192);
            bB1[nxt] = *(const bf16x8*)(wbB + (kt + 1) * 8192 + 128);
#pragma unroll
            for (int mt = 0; mt < 3; ++mt) {
                const int row = mt * 16 + l15;
                a[nxt][mt] =
                    *(const bf16x8*)(As + row * 256 + (((kt + 1) * 4 + hi) ^ gray(row)) * 8);
            }
        }
#pragma unroll
        for (int mt = 0; mt < 3; ++mt) {
            accA[mt][0] = MFMA16(a[cur][mt], bA0[cur], accA[mt][0]);
            accA[mt][1] = MFMA16(a[cur][mt], bA1[cur], accA[mt][1]);
            accB[mt][0] = MFMA16(a[cur][mt], bB0[cur], accB[mt][0]);
            accB[mt][1] = MFMA16(a[cur][mt], bB1[cur], accB[mt][1]);
        }
    }
}

// ---- single per-wave GEMM (value-L2 path): 3-slot B pipeline, A 1-deep ----
__device__ __forceinline__ void gemm256p(const bf16_t* __restrict__ As,
                                         const bf16_t* __restrict__ Wk,
                                         f32x4 acc[3][2], int w, int l) {
    const int l15 = l & 15, hi = l >> 4;
#pragma unroll
    for (int mt = 0; mt < 3; ++mt)
#pragma unroll
        for (int j = 0; j < 2; ++j) acc[mt][j] = (f32x4){0.f, 0.f, 0.f, 0.f};

    const bf16_t* wb = Wk + ((size_t)hi * 256 + w * 32 + l15) * 8;

    bf16x8 b0[3], b1[3];
    bf16x8 a[2][3];
    b0[0] = *(const bf16x8*)(wb);
    b1[0] = *(const bf16x8*)(wb + 128);
    b0[1] = *(const bf16x8*)(wb + 8192);
    b1[1] = *(const bf16x8*)(wb + 8192 + 128);
#pragma unroll
    for (int mt = 0; mt < 3; ++mt) {
        const int row = mt * 16 + l15;
        a[0][mt] = *(const bf16x8*)(As + row * 256 + (hi ^ gray(row)) * 8);
    }

#pragma unroll
    for (int kt = 0; kt < 8; ++kt) {
        const int cur = kt % 3, nx2 = (kt + 2) % 3;
        if (kt + 2 < 8) {
            b0[nx2] = *(const bf16x8*)(wb + (kt + 2) * 8192);
            b1[nx2] = *(const bf16x8*)(wb + (kt + 2) * 8192 + 128);
        }
        if (kt + 1 < 8) {
#pragma unroll
            for (int mt = 0; mt < 3; ++mt) {
                const int row = mt * 16 + l15;
                a[(kt + 1) & 1][mt] =
                    *(const bf16x8*)(As + row * 256 + (((kt + 1) * 4 + hi) ^ gray(row)) * 8);
            }
        }
#pragma unroll
        for (int mt = 0; mt < 3; ++mt) {
            acc[mt][0] = MFMA16(a[kt & 1][mt], b0[cur], acc[mt][0]);
            acc[mt][1] = MFMA16(a[kt & 1][mt], b1[cur], acc[mt][1]);
        }
    }
}

// epilogue: acc -> bias(+relu) -> bf16 LDS [48][256] swizzled
__device__ __forceinline__ void write_h(f32x4 acc[3][2], const float* __restrict__ bias,
                                        bool relu, bf16_t* __restrict__ dst, int w, int l) {
    const int l15 = l & 15, hi = l >> 4;
#pragma unroll
    for (int j = 0; j < 2; ++j) {
        const int col = w * 32 + j * 16 + l15;
        const float bv = bias[col];
#pragma unroll
        for (int mt = 0; mt < 3; ++mt)
#pragma unroll
            for (int r = 0; r < 4; ++r) {
                const int row = mt * 16 + hi * 4 + r;
                float v = acc[mt][j][r] + bv;
                if (relu) v = fmaxf(v, 0.f);
                dst[swz256(row, col)] = (bf16_t)v;
            }
    }
}

// score layer2: [48,256](LDS) @ W2k (k-major, 16 padded cols) -> ssc f32 [48][16] at coloff.
// rt = row-tile 0..2 (caller gates which waves run wm vs ws concurrently).
__device__ __forceinline__ void gemm_score(const bf16_t* __restrict__ As,
                                           const bf16_t* __restrict__ W2k,
                                           const float* __restrict__ b2,
                                           float* __restrict__ ssc, int coloff, int rt, int l) {
    const int l15 = l & 15, hi = l >> 4;
    const int row = rt * 16 + l15;
    const bf16_t* wb = W2k + ((size_t)hi * 16 + l15) * 8;
    bf16x8 b[3];
    b[0] = *(const bf16x8*)(wb);
    b[1] = *(const bf16x8*)(wb + 512);
    f32x4 acc = (f32x4){0.f, 0.f, 0.f, 0.f};
#pragma unroll
    for (int kt = 0; kt < 8; ++kt) {
        const int cur = kt % 3, nx2 = (kt + 2) % 3;
        if (kt + 2 < 8) b[nx2] = *(const bf16x8*)(wb + (kt + 2) * 512);
        bf16x8 a = *(const bf16x8*)(As + row * 256 + ((kt * 4 + hi) ^ gray(row)) * 8);
        acc = MFMA16(a, b[cur], acc);
    }
    if (l15 < 8) {
        const float bv = b2[l15];
#pragma unroll
        for (int r = 0; r < 4; ++r) {
            const int orow = rt * 16 + hi * 4 + r;
            ssc[orow * 16 + coloff + l15] = acc[r] + bv;
        }
    }
}

// segmented reduce over 48 staged rows; 512 threads: half h = tid>>8 takes rows
// [h*24, h*24+24), thread col = tid&255 (lane -> consecutive dwords: atomics coalesce).
template <bool WM>
__device__ __forceinline__ void reduce_seg(const bf16_t* __restrict__ sh,
                                           const float* __restrict__ ssc,
                                           const bf16_t* __restrict__ sx,
                                           const int* __restrict__ sseg,
                                           float* __restrict__ num, float* __restrict__ den,
                                           unsigned* __restrict__ pmax, int G) {
    const int col = threadIdx.x & 255;
    const int rbeg = (threadIdx.x >> 8) * 24;
    float av = 0.f, ad = 0.f;
    unsigned am = 0u;
    int gcur = sseg[rbeg];
    for (int r = rbeg; r < rbeg + 24; ++r) {
        const int g = sseg[r];
        if (g != gcur) {
            if ((unsigned)gcur < (unsigned)G) {
                atomicAdd(&num[(size_t)gcur * 256 + col], av);
                if (WM) {
                    if (col < 8) atomicAdd(&den[(size_t)gcur * 8 + col], ad);
                    atomicMax(&pmax[(size_t)gcur * 256 + col], am);
                }
            }
            av = 0.f; ad = 0.f; am = 0u; gcur = g;
        }
        const int si = swz256(r, col);
        const float v = (float)sh[si];
        const float wgt = ssc[r * 16 + (WM ? 0 : 8) + (col >> 5)];
        av += wgt * v;
        if (WM) {
            if (col < 8) ad += ssc[r * 16 + col];
            am = max(am, enc_max((float)sx[si]));
        }
    }
    if ((unsigned)gcur < (unsigned)G) {
        atomicAdd(&num[(size_t)gcur * 256 + col], av);
        if (WM) {
            if (col < 8) atomicAdd(&den[(size_t)gcur * 8 + col], ad);
            atomicMax(&pmax[(size_t)gcur * 256 + col], am);
        }
    }
}

__global__ __launch_bounds__(512, 4) void node_kernel(
    const float* __restrict__ X, const int* __restrict__ seg,
    const bf16_t* __restrict__ wt_sw1_wm, const bf16_t* __restrict__ wt_sw2_wm,
    const bf16_t* __restrict__ wt_vw1_wm, const bf16_t* __restrict__ wt_vw2_wm,
    const bf16_t* __restrict__ wt_sw1_ws, const bf16_t* __restrict__ wt_sw2_ws,
    const bf16_t* __restrict__ wt_vw1_ws, const bf16_t* __restrict__ wt_vw2_ws,
    const float* __restrict__ b_sw1_wm, const float* __restrict__ b_sw2_wm,
    const float* __restrict__ b_vw1_wm, const float* __restrict__ b_vw2_wm,
    const float* __restrict__ b_sw1_ws, const float* __restrict__ b_sw2_ws,
    const float* __restrict__ b_vw1_ws, const float* __restrict__ b_vw2_ws,
    float* __restrict__ num_wm, float* __restrict__ den_wm,
    float* __restrict__ acc_ws, unsigned* __restrict__ pmax, int N, int G) {
    __shared__ __align__(16) bf16_t sx[ROWS * 256];    // 24 KB
    __shared__ __align__(16) bf16_t shm[ROWS * 256];   // 24 KB (wm hidden)
    __shared__ __align__(16) bf16_t shs[ROWS * 256];   // 24 KB (ws hidden)
    __shared__ float ssc[ROWS * 16];                   // 3 KB
    __shared__ int sseg[ROWS];

    const int tid = threadIdx.x;
    const int w = tid >> 6, l = tid & 63;
    const int r0 = blockIdx.x * ROWS;

    // ---- stage X (f32 -> bf16, swizzled) + seg ids ----
#pragma unroll
    for (int i = 0; i < 3; ++i) {
        const int cid = tid + i * 512;
        const int row = cid >> 5, ch = cid & 31;
        bf16x8 o;
        if (r0 + row < N) {
            const float4* gp = (const float4*)(X + (size_t)(r0 + row) * 256 + ch * 8);
            o = cvt8(gp[0], gp[1]);
        } else {
            for (int j = 0; j < 8; ++j) o[j] = (bf16_t)0.f;
        }
        *(bf16x8*)(sx + row * 256 + (ch ^ gray(row)) * 8) = o;
    }
    if (tid < ROWS) sseg[tid] = (r0 + tid < N) ? seg[r0 + tid] : -1;
    __syncthreads();

    f32x4 accA[3][2], accB[3][2];

    // paired score-L1: one A-stream, both poolers
    gemm256_pair(sx, wt_sw1_wm, wt_sw1_ws, accA, accB, w, l);
    write_h(accA, b_sw1_wm, true, shm, w, l);
    write_h(accB, b_sw1_ws, true, shs, w, l);
    __syncthreads();

    // score-L2: wm on waves 0-2, ws on waves 4-6 (concurrent)
    if (w < 3)
        gemm_score(shm, wt_sw2_wm, b_sw2_wm, ssc, 0, w, l);
    else if (w >= 4 && w < 7)
        gemm_score(shs, wt_sw2_ws, b_sw2_ws, ssc, 8, w - 4, l);
    __syncthreads();

    // weights: cols 0-7 -> exp (softmax numerator); cols 8-15 -> sigmoid. 48*16=768.
#pragma unroll
    for (int i = 0; i < 2; ++i) {
        const int idx = tid + i * 512;
        if (idx < ROWS * 16) {
            const float v = ssc[idx];
            ssc[idx] = ((idx & 15) < 8) ? __expf(v) : 1.f / (1.f + __expf(-v));
        }
    }
    __syncthreads();

    // paired value-L1
    gemm256_pair(sx, wt_vw1_wm, wt_vw1_ws, accA, accB, w, l);
    write_h(accA, b_vw1_wm, true, shm, w, l);
    write_h(accB, b_vw1_ws, true, shs, w, l);
    __syncthreads();

    // wm value-L2 + reduce
    gemm256p(shm, wt_vw2_wm, accA, w, l);
    __syncthreads();                            // all waves done reading shm
    write_h(accA, b_vw2_wm, false, shm, w, l);  // in-place
    __syncthreads();
    reduce_seg<true>(shm, ssc, sx, sseg, num_wm, den_wm, pmax, G);
    // no barrier needed: next GEMM reads shs (untouched); reduce writes global only

    // ws value-L2 + reduce
    gemm256p(shs, wt_vw2_ws, accA, w, l);
    __syncthreads();                            // all waves done reading shs
    write_h(accA, b_vw2_ws, false, shs, w, l);  // in-place
    __syncthreads();
    reduce_seg<false>(shs, ssc, sx, sseg, acc_ws, nullptr, nullptr, G);
}

__global__ __launch_bounds__(256, 2) void graph_kernel(
    const float* __restrict__ num_wm, const float* __restrict__ den_wm,
    const float* __restrict__ acc_ws, const unsigned* __restrict__ pmax,
    const bf16_t* __restrict__ wt_comb_wm, const bf16_t* __restrict__ wt_comb_ws,
    const bf16_t* __restrict__ wt_comb_mx, const bf16_t* __restrict__ wt_final,
    float* __restrict__ out, int G) {
    __shared__ __align__(16) bf16_t sa[16 * 256];
    __shared__ __align__(16) bf16_t sraw[16 * 1536];

    const int tid = threadIdx.x, w = tid >> 6, l = tid & 63;
    const int l15 = l & 15, hi = l >> 4;
    const int g0 = blockIdx.x * 16;

    for (int src = 0; src < 3; ++src) {
#pragma unroll
        for (int i = 0; i < 2; ++i) {
            const int cid = tid + i * 256;
            const int row = cid >> 5, ch = cid & 31;
            const int g = g0 + row;
            bf16x8 o;
            if (g < G) {
                if (src == 0) {
                    const float4* np = (const float4*)(num_wm + (size_t)g * 256 + ch * 8);
                    float4 v0 = np[0], v1 = np[1];
                    const float d = den_wm[(size_t)g * 8 + (ch >> 2)];
                    const float rd = (d > 0.f) ? 1.f / d : 0.f;
                    o[0] = (bf16_t)(v0.x * rd); o[1] = (bf16_t)(v0.y * rd);
                    o[2] = (bf16_t)(v0.z * rd); o[3] = (bf16_t)(v0.w * rd);
                    o[4] = (bf16_t)(v1.x * rd); o[5] = (bf16_t)(v1.y * rd);
                    o[6] = (bf16_t)(v1.z * rd); o[7] = (bf16_t)(v1.w * rd);
                } else if (src == 1) {
                    const float4* np = (const float4*)(acc_ws + (size_t)g * 256 + ch * 8);
                    o = cvt8(np[0], np[1]);
                } else {
                    const unsigned* mp = pmax + (size_t)g * 256 + ch * 8;
#pragma unroll
                    for (int j = 0; j < 8; ++j) o[j] = (bf16_t)dec_max(mp[j]);
                }
            } else {
                for (int j = 0; j < 8; ++j) o[j] = (bf16_t)0.f;
            }
            *(bf16x8*)(sa + row * 256 + (ch ^ gray(row)) * 8) = o;
        }
        __syncthreads();

        // comb GEMM [16,256]@[256,512]; weights k-major [k>>3][n 0..511][k&7]
        const bf16_t* Wt = (src == 0) ? wt_comb_wm : ((src == 1) ? wt_comb_ws : wt_comb_mx);
        bf16x8 a[8];
#pragma unroll
        for (int kt = 0; kt < 8; ++kt)
            a[kt] = *(const bf16x8*)(sa + l15 * 256 + ((kt * 4 + hi) ^ gray(l15)) * 8);
        f32x4 acc[8];
#pragma unroll
        for (int j = 0; j < 8; ++j) acc[j] = (f32x4){0.f, 0.f, 0.f, 0.f};
#pragma unroll
        for (int kt = 0; kt < 8; ++kt) {
            bf16x8 b[8];
#pragma unroll
            for (int j = 0; j < 8; ++j) {
                const int ncol = (w * 8 + j) * 16 + l15;
                b[j] = *(const bf16x8*)(Wt + ((size_t)(kt * 4 + hi) * 512 + ncol) * 8);
            }
#pragma unroll
            for (int j = 0; j < 8; ++j) acc[j] = MFMA16(a[kt], b[j], acc[j]);
        }
#pragma unroll
        for (int j = 0; j < 8; ++j) {
            const int col = src * 512 + (w * 8 + j) * 16 + l15;
#pragma unroll
            for (int r = 0; r < 4; ++r) {
                const int row = hi * 4 + r;
                const float v = fmaxf(acc[j][r], 0.f);
                sraw[row * 1536 + ((((col >> 3) ^ gray(row)) << 3) | (col & 7))] = (bf16_t)v;
            }
        }
        __syncthreads();
    }

    // final: [16,1536] @ [1536,512]; weights k-major
    f32x4 facc[8];
#pragma unroll
    for (int j = 0; j < 8; ++j) facc[j] = (f32x4){0.f, 0.f, 0.f, 0.f};
    for (int kt = 0; kt < 48; ++kt) {
        bf16x8 a = *(const bf16x8*)(sraw + l15 * 1536 + ((kt * 4 + hi) ^ gray(l15)) * 8);
#pragma unroll
        for (int j = 0; j < 8; ++j) {
            const int ncol = (w * 8 + j) * 16 + l15;
            bf16x8 b = *(const bf16x8*)(wt_final + ((size_t)(kt * 4 + hi) * 512 + ncol) * 8);
            facc[j] = MFMA16(a, b, facc[j]);
        }
    }
#pragma unroll
    for (int j = 0; j < 8; ++j) {
        const int col = (w * 8 + j) * 16 + l15;
#pragma unroll
        for (int r = 0; r < 4; ++r) {
            const int row = hi * 4 + r;
            if (g0 + row < G) out[(size_t)(g0 + row) * 512 + col] = facc[j][r];
        }
    }
}

// merged k-major prep: 12 weight tensors in one launch.
struct PrepTab {
    const float* src[12];
    bf16_t* dst[12];
    int K[12], Nn[12], Nout[12];
    int base[13];
};

__global__ void prep_all(PrepTab t) {
    const int idx = blockIdx.x * blockDim.x + threadIdx.x;
    if (idx >= t.base[12]) return;
    int i = 0;
#pragma unroll
    for (int s = 0; s < 12; ++s)
        if (idx >= t.base[s + 1]) i = s + 1;
    const int local = idx - t.base[i];
    const int j = local & 7;
    const int rest = local >> 3;
    const int n = rest % t.Nout[i];
    const int kc = rest / t.Nout[i];
    const int k = kc * 8 + j;
    const float v = (n < t.Nn[i]) ? t.src[i][(size_t)k * t.Nn[i] + n] : 0.f;
    t.dst[i][local] = (bf16_t)v;
}

extern "C" void kernel_launch(void* const* d_in, const int* in_sizes, int n_in,
                              void* d_out, int out_size, void* d_ws, size_t ws_size,
                              hipStream_t stream) {
    const float* X = (const float*)d_in[0];
    const int* seg = (const int*)d_in[1];   // int32: harness passes integers as int
    const int N = in_sizes[1];
    const int G = out_size / 512;

    float* num_wm = (float*)d_ws;                       // G*256 f32
    float* acc_ws = num_wm + (size_t)G * 256;           // G*256 f32
    float* den_wm = acc_ws + (size_t)G * 256;           // G*8   f32
    unsigned* pmax = (unsigned*)(den_wm + (size_t)G * 8);  // G*256 u32
    bf16_t* wt = (bf16_t*)(pmax + (size_t)G * 256);

    bf16_t* wt_sw1_wm = wt;                   // 256*256
    bf16_t* wt_sw2_wm = wt_sw1_wm + 65536;    // 256*16 (zero-padded)
    bf16_t* wt_vw1_wm = wt_sw2_wm + 4096;
    bf16_t* wt_vw2_wm = wt_vw1_wm + 65536;
    bf16_t* wt_sw1_ws = wt_vw2_wm + 65536;
    bf16_t* wt_sw2_ws = wt_sw1_ws + 65536;
    bf16_t* wt_vw1_ws = wt_sw2_ws + 4096;
    bf16_t* wt_vw2_ws = wt_vw1_ws + 65536;
    bf16_t* wt_comb_wm = wt_vw2_ws + 65536;   // 256*512
    bf16_t* wt_comb_ws = wt_comb_wm + 131072;
    bf16_t* wt_comb_mx = wt_comb_ws + 131072;
    bf16_t* wt_final = wt_comb_mx + 131072;   // 1536*512

    const size_t accum_bytes = ((size_t)G * 256 * 3 + (size_t)G * 8) * 4;
    hipMemsetAsync(d_ws, 0, accum_bytes, stream);

    struct TT { int srcIdx; bf16_t* dst; int K, Nn, Nout; };
    const TT tt[12] = {
        {3,  wt_sw1_wm, 256, 256, 256},  {5,  wt_sw2_wm, 256, 8,   16},
        {7,  wt_vw1_wm, 256, 256, 256},  {9,  wt_vw2_wm, 256, 256, 256},
        {12, wt_sw1_ws, 256, 256, 256},  {14, wt_sw2_ws, 256, 8,   16},
        {16, wt_vw1_ws, 256, 256, 256},  {18, wt_vw2_ws, 256, 256, 256},
        {11, wt_comb_wm, 256, 512, 512}, {20, wt_comb_ws, 256, 512, 512},
        {21, wt_comb_mx, 256, 512, 512}, {22, wt_final, 1536, 512, 512},
    };
    PrepTab pt;
    int base = 0;
    for (int i = 0; i < 12; ++i) {
        pt.src[i] = (const float*)d_in[tt[i].srcIdx];
        pt.dst[i] = tt[i].dst;
        pt.K[i] = tt[i].K; pt.Nn[i] = tt[i].Nn; pt.Nout[i] = tt[i].Nout;
        pt.base[i] = base;
        base += tt[i].K * tt[i].Nout;
    }
    pt.base[12] = base;
    prep_all<<<(base + 255) / 256, 256, 0, stream>>>(pt);

    const int nb = (N + ROWS - 1) / ROWS;
    node_kernel<<<nb, 512, 0, stream>>>(
        X, seg,
        wt_sw1_wm, wt_sw2_wm, wt_vw1_wm, wt_vw2_wm,
        wt_sw1_ws, wt_sw2_ws, wt_vw1_ws, wt_vw2_ws,
        (const float*)d_in[4], (const float*)d_in[6], (const float*)d_in[8], (const float*)d_in[10],
        (const float*)d_in[13], (const float*)d_in[15], (const float*)d_in[17], (const float*)d_in[19],
        num_wm, den_wm, acc_ws, pmax, N, G);

    const int gb = (G + 15) / 16;
    graph_kernel<<<gb, 256, 0, stream>>>(num_wm, den_wm, acc_ws, pmax,
                                         wt_comb_wm, wt_comb_ws, wt_comb_mx, wt_final,
                                         (float*)d_out, G);
}

// Round 18
// 317.866 us; speedup vs baseline: 1.1166x; 1.1166x over previous
//
#include <hip/hip_runtime.h>
#include <hip/hip_bf16.h>

typedef __bf16 bf16_t;
typedef __bf16 bf16x8 __attribute__((ext_vector_type(8)));
typedef float  f32x4  __attribute__((ext_vector_type(4)));

#define MFMA16(a, b, c) __builtin_amdgcn_mfma_f32_16x16x32_bf16((a), (b), (c), 0, 0, 0)

#define ROWS 48   // 48-row tile; 2 LDS tiles ~50KB -> 2 blocks/CU; VGPR 64+24acc -> 4 waves/SIMD

// Gray-code bank swizzle for [rows][256] bf16 LDS tiles (row stride 512B).
__device__ __forceinline__ int gray(int row) { return (row ^ (row >> 1)) & 7; }
__device__ __forceinline__ int swz256(int row, int col) {
    return row * 256 + ((((col >> 3) ^ gray(row)) << 3) | (col & 7));
}

__device__ __forceinline__ bf16x8 cvt8(float4 a, float4 b) {
    bf16x8 o;
    o[0] = (bf16_t)a.x; o[1] = (bf16_t)a.y; o[2] = (bf16_t)a.z; o[3] = (bf16_t)a.w;
    o[4] = (bf16_t)b.x; o[5] = (bf16_t)b.y; o[6] = (bf16_t)b.z; o[7] = (bf16_t)b.w;
    return o;
}

__device__ __forceinline__ unsigned enc_max(float x) {
    unsigned b = __float_as_uint(x);
    return (b & 0x80000000u) ? ~b : (b | 0x80000000u);
}
__device__ __forceinline__ float dec_max(unsigned e) {
    if (e == 0u) return 0.0f;
    return (e & 0x80000000u) ? __uint_as_float(e ^ 0x80000000u) : __uint_as_float(~e);
}

// ---- per-wave GEMM: [48,256](LDS A, gray-swizzled) @ Wk (k-major global) ----
// 8 waves; wave w -> out-cols [w*32, w*32+32). B 3-slot rotating prefetch
// (2 K-steps ahead), A 1-deep. All indices static after unroll. 64 VGPR total.
__device__ __forceinline__ void gemm256p(const bf16_t* __restrict__ As,
                                         const bf16_t* __restrict__ Wk,
                                         f32x4 acc[3][2], int w, int l) {
    const int l15 = l & 15, hi = l >> 4;
#pragma unroll
    for (int mt = 0; mt < 3; ++mt)
#pragma unroll
        for (int j = 0; j < 2; ++j) acc[mt][j] = (f32x4){0.f, 0.f, 0.f, 0.f};

    const bf16_t* wb = Wk + ((size_t)hi * 256 + w * 32 + l15) * 8;

    bf16x8 b0[3], b1[3];
    bf16x8 a[2][3];
    b0[0] = *(const bf16x8*)(wb);
    b1[0] = *(const bf16x8*)(wb + 128);
    b0[1] = *(const bf16x8*)(wb + 8192);
    b1[1] = *(const bf16x8*)(wb + 8192 + 128);
#pragma unroll
    for (int mt = 0; mt < 3; ++mt) {
        const int row = mt * 16 + l15;
        a[0][mt] = *(const bf16x8*)(As + row * 256 + (hi ^ gray(row)) * 8);
    }

#pragma unroll
    for (int kt = 0; kt < 8; ++kt) {
        const int cur = kt % 3, nx2 = (kt + 2) % 3;
        if (kt + 2 < 8) {
            b0[nx2] = *(const bf16x8*)(wb + (kt + 2) * 8192);
            b1[nx2] = *(const bf16x8*)(wb + (kt + 2) * 8192 + 128);
        }
        if (kt + 1 < 8) {
#pragma unroll
            for (int mt = 0; mt < 3; ++mt) {
                const int row = mt * 16 + l15;
                a[(kt + 1) & 1][mt] =
                    *(const bf16x8*)(As + row * 256 + (((kt + 1) * 4 + hi) ^ gray(row)) * 8);
            }
        }
#pragma unroll
        for (int mt = 0; mt < 3; ++mt) {
            acc[mt][0] = MFMA16(a[kt & 1][mt], b0[cur], acc[mt][0]);
            acc[mt][1] = MFMA16(a[kt & 1][mt], b1[cur], acc[mt][1]);
        }
    }
}

// epilogue: acc -> bias(+relu) -> bf16 LDS [48][256] swizzled
__device__ __forceinline__ void write_h(f32x4 acc[3][2], const float* __restrict__ bias,
                                        bool relu, bf16_t* __restrict__ dst, int w, int l) {
    const int l15 = l & 15, hi = l >> 4;
#pragma unroll
    for (int j = 0; j < 2; ++j) {
        const int col = w * 32 + j * 16 + l15;
        const float bv = bias[col];
#pragma unroll
        for (int mt = 0; mt < 3; ++mt)
#pragma unroll
            for (int r = 0; r < 4; ++r) {
                const int row = mt * 16 + hi * 4 + r;
                float v = acc[mt][j][r] + bv;
                if (relu) v = fmaxf(v, 0.f);
                dst[swz256(row, col)] = (bf16_t)v;
            }
    }
}

// score layer2: [48,256](LDS) @ W2k (k-major, 16 padded cols) -> ssc f32 [48][8]
// waves 0..2 participate (row-tile = w)
__device__ __forceinline__ void gemm_score(const bf16_t* __restrict__ As,
                                           const bf16_t* __restrict__ W2k,
                                           const float* __restrict__ b2,
                                           float* __restrict__ ssc, int w, int l) {
    if (w >= 3) return;
    const int l15 = l & 15, hi = l >> 4;
    const int row = w * 16 + l15;
    const bf16_t* wb = W2k + ((size_t)hi * 16 + l15) * 8;
    bf16x8 b[3];
    b[0] = *(const bf16x8*)(wb);
    b[1] = *(const bf16x8*)(wb + 512);
    f32x4 acc = (f32x4){0.f, 0.f, 0.f, 0.f};
#pragma unroll
    for (int kt = 0; kt < 8; ++kt) {
        const int cur = kt % 3, nx2 = (kt + 2) % 3;
        if (kt + 2 < 8) b[nx2] = *(const bf16x8*)(wb + (kt + 2) * 512);
        bf16x8 a = *(const bf16x8*)(As + row * 256 + ((kt * 4 + hi) ^ gray(row)) * 8);
        acc = MFMA16(a, b[cur], acc);
    }
    if (l15 < 8) {
        const float bv = b2[l15];
#pragma unroll
        for (int r = 0; r < 4; ++r) {
            const int orow = w * 16 + hi * 4 + r;
            ssc[orow * 8 + l15] = acc[r] + bv;
        }
    }
}

// segmented reduce over 48 staged rows; 512 threads: half h = tid>>8 takes rows
// [h*24, h*24+24), thread col = tid&255 (lane -> consecutive dwords: atomics coalesce).
// WM blocks: weighted num + den. WS blocks: weighted num + X-max.
template <bool WM>
__device__ __forceinline__ void reduce_seg(const bf16_t* __restrict__ sh,
                                           const float* __restrict__ ssc,
                                           const bf16_t* __restrict__ sx,
                                           const int* __restrict__ sseg,
                                           float* __restrict__ num, float* __restrict__ den,
                                           unsigned* __restrict__ pmax, int G) {
    const int col = threadIdx.x & 255;
    const int rbeg = (threadIdx.x >> 8) * 24;
    float av = 0.f, ad = 0.f;
    unsigned am = 0u;
    int gcur = sseg[rbeg];
    for (int r = rbeg; r < rbeg + 24; ++r) {
        const int g = sseg[r];
        if (g != gcur) {
            if ((unsigned)gcur < (unsigned)G) {
                atomicAdd(&num[(size_t)gcur * 256 + col], av);
                if (WM) {
                    if (col < 8) atomicAdd(&den[(size_t)gcur * 8 + col], ad);
                } else {
                    atomicMax(&pmax[(size_t)gcur * 256 + col], am);
                }
            }
            av = 0.f; ad = 0.f; am = 0u; gcur = g;
        }
        const int si = swz256(r, col);
        const float v = (float)sh[si];
        const float wgt = ssc[r * 8 + (col >> 5)];
        av += wgt * v;
        if (WM) {
            if (col < 8) ad += ssc[r * 8 + col];
        } else {
            am = max(am, enc_max((float)sx[si]));
        }
    }
    if ((unsigned)gcur < (unsigned)G) {
        atomicAdd(&num[(size_t)gcur * 256 + col], av);
        if (WM) {
            if (col < 8) atomicAdd(&den[(size_t)gcur * 8 + col], ad);
        } else {
            atomicMax(&pmax[(size_t)gcur * 256 + col], am);
        }
    }
}

// grid (ceil(N/48), 2): blockIdx.y 0 = weighted_mean pooler, 1 = weighted_sum pooler.
// Per-block chain: stage X -> score L1 -> score L2 -> act -> value L1 -> value L2 -> reduce.
// Same wave geometry as the R16 best (8 waves x 32-col stripes); 6 barriers vs 11.
__global__ __launch_bounds__(512, 3) void node_kernel(
    const float* __restrict__ X, const int* __restrict__ seg,
    const bf16_t* __restrict__ wt_sw1_wm, const bf16_t* __restrict__ wt_sw2_wm,
    const bf16_t* __restrict__ wt_vw1_wm, const bf16_t* __restrict__ wt_vw2_wm,
    const bf16_t* __restrict__ wt_sw1_ws, const bf16_t* __restrict__ wt_sw2_ws,
    const bf16_t* __restrict__ wt_vw1_ws, const bf16_t* __restrict__ wt_vw2_ws,
    const float* __restrict__ b_sw1_wm, const float* __restrict__ b_sw2_wm,
    const float* __restrict__ b_vw1_wm, const float* __restrict__ b_vw2_wm,
    const float* __restrict__ b_sw1_ws, const float* __restrict__ b_sw2_ws,
    const float* __restrict__ b_vw1_ws, const float* __restrict__ b_vw2_ws,
    float* __restrict__ num_wm, float* __restrict__ den_wm,
    float* __restrict__ acc_ws, unsigned* __restrict__ pmax, int N, int G) {
    __shared__ __align__(16) bf16_t sx[ROWS * 256];    // 24 KB
    __shared__ __align__(16) bf16_t sh[ROWS * 256];    // 24 KB
    __shared__ float ssc[ROWS * 8];                    // 1.5 KB
    __shared__ int sseg[ROWS];

    const int tid = threadIdx.x;
    const int w = tid >> 6, l = tid & 63;
    const int r0 = blockIdx.x * ROWS;
    const bool wm = (blockIdx.y == 0);

    const bf16_t* Ws1 = wm ? wt_sw1_wm : wt_sw1_ws;
    const bf16_t* Ws2 = wm ? wt_sw2_wm : wt_sw2_ws;
    const bf16_t* Wv1 = wm ? wt_vw1_wm : wt_vw1_ws;
    const bf16_t* Wv2 = wm ? wt_vw2_wm : wt_vw2_ws;
    const float* bs1 = wm ? b_sw1_wm : b_sw1_ws;
    const float* bs2 = wm ? b_sw2_wm : b_sw2_ws;
    const float* bv1 = wm ? b_vw1_wm : b_vw1_ws;
    const float* bv2 = wm ? b_vw2_wm : b_vw2_ws;

    // ---- stage X (f32 -> bf16, swizzled) + seg ids ----
#pragma unroll
    for (int i = 0; i < 3; ++i) {
        const int cid = tid + i * 512;
        const int row = cid >> 5, ch = cid & 31;
        bf16x8 o;
        if (r0 + row < N) {
            const float4* gp = (const float4*)(X + (size_t)(r0 + row) * 256 + ch * 8);
            o = cvt8(gp[0], gp[1]);
        } else {
            for (int j = 0; j < 8; ++j) o[j] = (bf16_t)0.f;
        }
        *(bf16x8*)(sx + row * 256 + (ch ^ gray(row)) * 8) = o;
    }
    if (tid < ROWS) sseg[tid] = (r0 + tid < N) ? seg[r0 + tid] : -1;
    __syncthreads();

    f32x4 acc[3][2];

    // score MLP
    gemm256p(sx, Ws1, acc, w, l);
    write_h(acc, bs1, true, sh, w, l);
    __syncthreads();
    gemm_score(sh, Ws2, bs2, ssc, w, l);
    __syncthreads();

    // weights: wm -> exp (softmax numerator, no max-sub needed); ws -> sigmoid. 48*8=384.
    if (tid < ROWS * 8) {
        const float v = ssc[tid];
        ssc[tid] = wm ? __expf(v) : 1.f / (1.f + __expf(-v));
    }
    __syncthreads();

    // value MLP
    gemm256p(sx, Wv1, acc, w, l);
    write_h(acc, bv1, true, sh, w, l);
    __syncthreads();
    gemm256p(sh, Wv2, acc, w, l);
    __syncthreads();                      // all waves done reading sh
    write_h(acc, bv2, false, sh, w, l);   // in-place
    __syncthreads();

    if (wm)
        reduce_seg<true>(sh, ssc, sx, sseg, num_wm, den_wm, nullptr, G);
    else
        reduce_seg<false>(sh, ssc, sx, sseg, acc_ws, nullptr, pmax, G);
}

__global__ __launch_bounds__(256, 2) void graph_kernel(
    const float* __restrict__ num_wm, const float* __restrict__ den_wm,
    const float* __restrict__ acc_ws, const unsigned* __restrict__ pmax,
    const bf16_t* __restrict__ wt_comb_wm, const bf16_t* __restrict__ wt_comb_ws,
    const bf16_t* __restrict__ wt_comb_mx, const bf16_t* __restrict__ wt_final,
    float* __restrict__ out, int G) {
    __shared__ __align__(16) bf16_t sa[16 * 256];
    __shared__ __align__(16) bf16_t sraw[16 * 1536];

    const int tid = threadIdx.x, w = tid >> 6, l = tid & 63;
    const int l15 = l & 15, hi = l >> 4;
    const int g0 = blockIdx.x * 16;

    for (int src = 0; src < 3; ++src) {
#pragma unroll
        for (int i = 0; i < 2; ++i) {
            const int cid = tid + i * 256;
            const int row = cid >> 5, ch = cid & 31;
            const int g = g0 + row;
            bf16x8 o;
            if (g < G) {
                if (src == 0) {
                    const float4* np = (const float4*)(num_wm + (size_t)g * 256 + ch * 8);
                    float4 v0 = np[0], v1 = np[1];
                    const float d = den_wm[(size_t)g * 8 + (ch >> 2)];
                    const float rd = (d > 0.f) ? 1.f / d : 0.f;
                    o[0] = (bf16_t)(v0.x * rd); o[1] = (bf16_t)(v0.y * rd);
                    o[2] = (bf16_t)(v0.z * rd); o[3] = (bf16_t)(v0.w * rd);
                    o[4] = (bf16_t)(v1.x * rd); o[5] = (bf16_t)(v1.y * rd);
                    o[6] = (bf16_t)(v1.z * rd); o[7] = (bf16_t)(v1.w * rd);
                } else if (src == 1) {
                    const float4* np = (const float4*)(acc_ws + (size_t)g * 256 + ch * 8);
                    o = cvt8(np[0], np[1]);
                } else {
                    const unsigned* mp = pmax + (size_t)g * 256 + ch * 8;
#pragma unroll
                    for (int j = 0; j < 8; ++j) o[j] = (bf16_t)dec_max(mp[j]);
                }
            } else {
                for (int j = 0; j < 8; ++j) o[j] = (bf16_t)0.f;
            }
            *(bf16x8*)(sa + row * 256 + (ch ^ gray(row)) * 8) = o;
        }
        __syncthreads();

        // comb GEMM [16,256]@[256,512]; weights k-major [k>>3][n 0..511][k&7]
        const bf16_t* Wt = (src == 0) ? wt_comb_wm : ((src == 1) ? wt_comb_ws : wt_comb_mx);
        bf16x8 a[8];
#pragma unroll
        for (int kt = 0; kt < 8; ++kt)
            a[kt] = *(const bf16x8*)(sa + l15 * 256 + ((kt * 4 + hi) ^ gray(l15)) * 8);
        f32x4 acc[8];
#pragma unroll
        for (int j = 0; j < 8; ++j) acc[j] = (f32x4){0.f, 0.f, 0.f, 0.f};
#pragma unroll
        for (int kt = 0; kt < 8; ++kt) {
            bf16x8 b[8];
#pragma unroll
            for (int j = 0; j < 8; ++j) {
                const int ncol = (w * 8 + j) * 16 + l15;
                b[j] = *(const bf16x8*)(Wt + ((size_t)(kt * 4 + hi) * 512 + ncol) * 8);
            }
#pragma unroll
            for (int j = 0; j < 8; ++j) acc[j] = MFMA16(a[kt], b[j], acc[j]);
        }
#pragma unroll
        for (int j = 0; j < 8; ++j) {
            const int col = src * 512 + (w * 8 + j) * 16 + l15;
#pragma unroll
            for (int r = 0; r < 4; ++r) {
                const int row = hi * 4 + r;
                const float v = fmaxf(acc[j][r], 0.f);
                sraw[row * 1536 + ((((col >> 3) ^ gray(row)) << 3) | (col & 7))] = (bf16_t)v;
            }
        }
        __syncthreads();
    }

    // final: [16,1536] @ [1536,512]; weights k-major
    f32x4 facc[8];
#pragma unroll
    for (int j = 0; j < 8; ++j) facc[j] = (f32x4){0.f, 0.f, 0.f, 0.f};
    for (int kt = 0; kt < 48; ++kt) {
        bf16x8 a = *(const bf16x8*)(sraw + l15 * 1536 + ((kt * 4 + hi) ^ gray(l15)) * 8);
#pragma unroll
        for (int j = 0; j < 8; ++j) {
            const int ncol = (w * 8 + j) * 16 + l15;
            bf16x8 b = *(const bf16x8*)(wt_final + ((size_t)(kt * 4 + hi) * 512 + ncol) * 8);
            facc[j] = MFMA16(a, b, facc[j]);
        }
    }
#pragma unroll
    for (int j = 0; j < 8; ++j) {
        const int col = (w * 8 + j) * 16 + l15;
#pragma unroll
        for (int r = 0; r < 4; ++r) {
            const int row = hi * 4 + r;
            if (g0 + row < G) out[(size_t)(g0 + row) * 512 + col] = facc[j][r];
        }
    }
}

// merged k-major prep: 12 weight tensors in one launch.
struct PrepTab {
    const float* src[12];
    bf16_t* dst[12];
    int K[12], Nn[12], Nout[12];
    int base[13];
};

__global__ void prep_all(PrepTab t) {
    const int idx = blockIdx.x * blockDim.x + threadIdx.x;
    if (idx >= t.base[12]) return;
    int i = 0;
#pragma unroll
    for (int s = 0; s < 12; ++s)
        if (idx >= t.base[s + 1]) i = s + 1;
    const int local = idx - t.base[i];
    const int j = local & 7;
    const int rest = local >> 3;
    const int n = rest % t.Nout[i];
    const int kc = rest / t.Nout[i];
    const int k = kc * 8 + j;
    const float v = (n < t.Nn[i]) ? t.src[i][(size_t)k * t.Nn[i] + n] : 0.f;
    t.dst[i][local] = (bf16_t)v;
}

extern "C" void kernel_launch(void* const* d_in, const int* in_sizes, int n_in,
                              void* d_out, int out_size, void* d_ws, size_t ws_size,
                              hipStream_t stream) {
    const float* X = (const float*)d_in[0];
    const int* seg = (const int*)d_in[1];   // int32: harness passes integers as int
    const int N = in_sizes[1];
    const int G = out_size / 512;

    float* num_wm = (float*)d_ws;                       // G*256 f32
    float* acc_ws = num_wm + (size_t)G * 256;           // G*256 f32
    float* den_wm = acc_ws + (size_t)G * 256;           // G*8   f32
    unsigned* pmax = (unsigned*)(den_wm + (size_t)G * 8);  // G*256 u32
    bf16_t* wt = (bf16_t*)(pmax + (size_t)G * 256);

    bf16_t* wt_sw1_wm = wt;                   // 256*256
    bf16_t* wt_sw2_wm = wt_sw1_wm + 65536;    // 256*16 (zero-padded)
    bf16_t* wt_vw1_wm = wt_sw2_wm + 4096;
    bf16_t* wt_vw2_wm = wt_vw1_wm + 65536;
    bf16_t* wt_sw1_ws = wt_vw2_wm + 65536;
    bf16_t* wt_sw2_ws = wt_sw1_ws + 65536;
    bf16_t* wt_vw1_ws = wt_sw2_ws + 4096;
    bf16_t* wt_vw2_ws = wt_vw1_ws + 65536;
    bf16_t* wt_comb_wm = wt_vw2_ws + 65536;   // 256*512
    bf16_t* wt_comb_ws = wt_comb_wm + 131072;
    bf16_t* wt_comb_mx = wt_comb_ws + 131072;
    bf16_t* wt_final = wt_comb_mx + 131072;   // 1536*512

    const size_t accum_bytes = ((size_t)G * 256 * 3 + (size_t)G * 8) * 4;
    hipMemsetAsync(d_ws, 0, accum_bytes, stream);

    struct TT { int srcIdx; bf16_t* dst; int K, Nn, Nout; };
    const TT tt[12] = {
        {3,  wt_sw1_wm, 256, 256, 256},  {5,  wt_sw2_wm, 256, 8,   16},
        {7,  wt_vw1_wm, 256, 256, 256},  {9,  wt_vw2_wm, 256, 256, 256},
        {12, wt_sw1_ws, 256, 256, 256},  {14, wt_sw2_ws, 256, 8,   16},
        {16, wt_vw1_ws, 256, 256, 256},  {18, wt_vw2_ws, 256, 256, 256},
        {11, wt_comb_wm, 256, 512, 512}, {20, wt_comb_ws, 256, 512, 512},
        {21, wt_comb_mx, 256, 512, 512}, {22, wt_final, 1536, 512, 512},
    };
    PrepTab pt;
    int base = 0;
    for (int i = 0; i < 12; ++i) {
        pt.src[i] = (const float*)d_in[tt[i].srcIdx];
        pt.dst[i] = tt[i].dst;
        pt.K[i] = tt[i].K; pt.Nn[i] = tt[i].Nn; pt.Nout[i] = tt[i].Nout;
        pt.base[i] = base;
        base += tt[i].K * tt[i].Nout;
    }
    pt.base[12] = base;
    prep_all<<<(base + 255) / 256, 256, 0, stream>>>(pt);

    const int nb = (N + ROWS - 1) / ROWS;
    dim3 ngrid(nb, 2);
    node_kernel<<<ngrid, 512, 0, stream>>>(
        X, seg,
        wt_sw1_wm, wt_sw2_wm, wt_vw1_wm, wt_vw2_wm,
        wt_sw1_ws, wt_sw2_ws, wt_vw1_ws, wt_vw2_ws,
        (const float*)d_in[4], (const float*)d_in[6], (const float*)d_in[8], (const float*)d_in[10],
        (const float*)d_in[13], (const float*)d_in[15], (const float*)d_in[17], (const float*)d_in[19],
        num_wm, den_wm, acc_ws, pmax, N, G);

    const int gb = (G + 15) / 16;
    graph_kernel<<<gb, 256, 0, stream>>>(num_wm, den_wm, acc_ws, pmax,
                                         wt_comb_wm, wt_comb_ws, wt_comb_mx, wt_final,
                                         (float*)d_out, G);
}

// Round 19
// 302.552 us; speedup vs baseline: 1.1732x; 1.0506x over previous
//
#include <hip/hip_runtime.h>
#include <hip/hip_bf16.h>

typedef __bf16 bf16_t;
typedef __bf16 bf16x8 __attribute__((ext_vector_type(8)));
typedef float  f32x4  __attribute__((ext_vector_type(4)));

#define MFMA16(a, b, c) __builtin_amdgcn_mfma_f32_16x16x32_bf16((a), (b), (c), 0, 0, 0)

#define ROWS 48   // 48-row tile: 52.7KB LDS, 2 blocks/CU, VGPR=64 -> 4 waves/SIMD (best config)

// Gray-code bank swizzle for [rows][256] bf16 LDS tiles (row stride 512B).
__device__ __forceinline__ int gray(int row) { return (row ^ (row >> 1)) & 7; }
__device__ __forceinline__ int swz256(int row, int col) {
    return row * 256 + ((((col >> 3) ^ gray(row)) << 3) | (col & 7));
}

__device__ __forceinline__ bf16x8 cvt8(float4 a, float4 b) {
    bf16x8 o;
    o[0] = (bf16_t)a.x; o[1] = (bf16_t)a.y; o[2] = (bf16_t)a.z; o[3] = (bf16_t)a.w;
    o[4] = (bf16_t)b.x; o[5] = (bf16_t)b.y; o[6] = (bf16_t)b.z; o[7] = (bf16_t)b.w;
    return o;
}

__device__ __forceinline__ unsigned enc_max(float x) {
    unsigned b = __float_as_uint(x);
    return (b & 0x80000000u) ? ~b : (b | 0x80000000u);
}
__device__ __forceinline__ float dec_max(unsigned e) {
    if (e == 0u) return 0.0f;
    return (e & 0x80000000u) ? __uint_as_float(e ^ 0x80000000u) : __uint_as_float(~e);
}

// ---- per-wave GEMM: [48,256](LDS A, gray-swizzled) @ Wk (k-major global) ----
// 8 waves; wave w -> out-cols [w*32, w*32+32). B 3-slot rotating prefetch
// (2 K-steps ahead), A 1-deep. All indices static after unroll. 64 VGPR total.
__device__ __forceinline__ void gemm256p(const bf16_t* __restrict__ As,
                                         const bf16_t* __restrict__ Wk,
                                         f32x4 acc[3][2], int w, int l) {
    const int l15 = l & 15, hi = l >> 4;
#pragma unroll
    for (int mt = 0; mt < 3; ++mt)
#pragma unroll
        for (int j = 0; j < 2; ++j) acc[mt][j] = (f32x4){0.f, 0.f, 0.f, 0.f};

    const bf16_t* wb = Wk + ((size_t)hi * 256 + w * 32 + l15) * 8;

    bf16x8 b0[3], b1[3];
    bf16x8 a[2][3];
    b0[0] = *(const bf16x8*)(wb);
    b1[0] = *(const bf16x8*)(wb + 128);
    b0[1] = *(const bf16x8*)(wb + 8192);
    b1[1] = *(const bf16x8*)(wb + 8192 + 128);
#pragma unroll
    for (int mt = 0; mt < 3; ++mt) {
        const int row = mt * 16 + l15;
        a[0][mt] = *(const bf16x8*)(As + row * 256 + (hi ^ gray(row)) * 8);
    }

#pragma unroll
    for (int kt = 0; kt < 8; ++kt) {
        const int cur = kt % 3, nx2 = (kt + 2) % 3;
        if (kt + 2 < 8) {
            b0[nx2] = *(const bf16x8*)(wb + (kt + 2) * 8192);
            b1[nx2] = *(const bf16x8*)(wb + (kt + 2) * 8192 + 128);
        }
        if (kt + 1 < 8) {
#pragma unroll
            for (int mt = 0; mt < 3; ++mt) {
                const int row = mt * 16 + l15;
                a[(kt + 1) & 1][mt] =
                    *(const bf16x8*)(As + row * 256 + (((kt + 1) * 4 + hi) ^ gray(row)) * 8);
            }
        }
#pragma unroll
        for (int mt = 0; mt < 3; ++mt) {
            acc[mt][0] = MFMA16(a[kt & 1][mt], b0[cur], acc[mt][0]);
            acc[mt][1] = MFMA16(a[kt & 1][mt], b1[cur], acc[mt][1]);
        }
    }
}

// epilogue: acc -> bias(+relu) -> bf16 LDS [48][256] swizzled
__device__ __forceinline__ void write_h(f32x4 acc[3][2], const float* __restrict__ bias,
                                        bool relu, bf16_t* __restrict__ dst, int w, int l) {
    const int l15 = l & 15, hi = l >> 4;
#pragma unroll
    for (int j = 0; j < 2; ++j) {
        const int col = w * 32 + j * 16 + l15;
        const float bv = bias[col];
#pragma unroll
        for (int mt = 0; mt < 3; ++mt)
#pragma unroll
            for (int r = 0; r < 4; ++r) {
                const int row = mt * 16 + hi * 4 + r;
                float v = acc[mt][j][r] + bv;
                if (relu) v = fmaxf(v, 0.f);
                dst[swz256(row, col)] = (bf16_t)v;
            }
    }
}

// score layer2: [48,256](LDS) @ W2k (k-major, 16 padded cols) -> ssc f32 [48][16]
// waves 0..2 participate (row-tile = w)
__device__ __forceinline__ void gemm_score(const bf16_t* __restrict__ As,
                                           const bf16_t* __restrict__ W2k,
                                           const float* __restrict__ b2,
                                           float* __restrict__ ssc, int coloff, int w, int l) {
    if (w >= 3) return;
    const int l15 = l & 15, hi = l >> 4;
    const int row = w * 16 + l15;
    const bf16_t* wb = W2k + ((size_t)hi * 16 + l15) * 8;
    bf16x8 b[3];
    b[0] = *(const bf16x8*)(wb);
    b[1] = *(const bf16x8*)(wb + 512);
    f32x4 acc = (f32x4){0.f, 0.f, 0.f, 0.f};
#pragma unroll
    for (int kt = 0; kt < 8; ++kt) {
        const int cur = kt % 3, nx2 = (kt + 2) % 3;
        if (kt + 2 < 8) b[nx2] = *(const bf16x8*)(wb + (kt + 2) * 512);
        bf16x8 a = *(const bf16x8*)(As + row * 256 + ((kt * 4 + hi) ^ gray(row)) * 8);
        acc = MFMA16(a, b[cur], acc);
    }
    if (l15 < 8) {
        const float bv = b2[l15];
#pragma unroll
        for (int r = 0; r < 4; ++r) {
            const int orow = w * 16 + hi * 4 + r;
            ssc[orow * 16 + coloff + l15] = acc[r] + bv;
        }
    }
}

// segmented reduce over 48 staged rows; 512 threads: half h = tid>>8 takes rows
// [h*24, h*24+24), thread col = tid&255 (lane -> consecutive dwords: atomics coalesce).
template <bool WM>
__device__ __forceinline__ void reduce_seg(const bf16_t* __restrict__ sh,
                                           const float* __restrict__ ssc,
                                           const bf16_t* __restrict__ sx,
                                           const int* __restrict__ sseg,
                                           float* __restrict__ num, float* __restrict__ den,
                                           unsigned* __restrict__ pmax, int G) {
    const int col = threadIdx.x & 255;
    const int rbeg = (threadIdx.x >> 8) * 24;
    float av = 0.f, ad = 0.f;
    unsigned am = 0u;
    int gcur = sseg[rbeg];
    for (int r = rbeg; r < rbeg + 24; ++r) {
        const int g = sseg[r];
        if (g != gcur) {
            if ((unsigned)gcur < (unsigned)G) {
                atomicAdd(&num[(size_t)gcur * 256 + col], av);
                if (WM) {
                    if (col < 8) atomicAdd(&den[(size_t)gcur * 8 + col], ad);
                    atomicMax(&pmax[(size_t)gcur * 256 + col], am);
                }
            }
            av = 0.f; ad = 0.f; am = 0u; gcur = g;
        }
        const int si = swz256(r, col);
        const float v = (float)sh[si];
        const float wgt = ssc[r * 16 + (WM ? 0 : 8) + (col >> 5)];
        av += wgt * v;
        if (WM) {
            if (col < 8) ad += ssc[r * 16 + col];
            am = max(am, enc_max((float)sx[si]));
        }
    }
    if ((unsigned)gcur < (unsigned)G) {
        atomicAdd(&num[(size_t)gcur * 256 + col], av);
        if (WM) {
            if (col < 8) atomicAdd(&den[(size_t)gcur * 8 + col], ad);
            atomicMax(&pmax[(size_t)gcur * 256 + col], am);
        }
    }
}

__global__ __launch_bounds__(512, 3) void node_kernel(
    const float* __restrict__ X, const int* __restrict__ seg,
    const bf16_t* __restrict__ wt_sw1_wm, const bf16_t* __restrict__ wt_sw2_wm,
    const bf16_t* __restrict__ wt_vw1_wm, const bf16_t* __restrict__ wt_vw2_wm,
    const bf16_t* __restrict__ wt_sw1_ws, const bf16_t* __restrict__ wt_sw2_ws,
    const bf16_t* __restrict__ wt_vw1_ws, const bf16_t* __restrict__ wt_vw2_ws,
    const float* __restrict__ b_sw1_wm, const float* __restrict__ b_sw2_wm,
    const float* __restrict__ b_vw1_wm, const float* __restrict__ b_vw2_wm,
    const float* __restrict__ b_sw1_ws, const float* __restrict__ b_sw2_ws,
    const float* __restrict__ b_vw1_ws, const float* __restrict__ b_vw2_ws,
    float* __restrict__ num_wm, float* __restrict__ den_wm,
    float* __restrict__ acc_ws, unsigned* __restrict__ pmax, int N, int G) {
    __shared__ __align__(16) bf16_t sx[ROWS * 256];    // 24 KB
    __shared__ __align__(16) bf16_t sh[ROWS * 256];    // 24 KB
    __shared__ float ssc[ROWS * 16];                   // 3 KB
    __shared__ int sseg[ROWS];

    const int tid = threadIdx.x;
    const int w = tid >> 6, l = tid & 63;
    const int r0 = blockIdx.x * ROWS;

    // ---- stage X (f32 -> bf16, swizzled) + seg ids ----
#pragma unroll
    for (int i = 0; i < 3; ++i) {
        const int cid = tid + i * 512;
        const int row = cid >> 5, ch = cid & 31;
        bf16x8 o;
        if (r0 + row < N) {
            const float4* gp = (const float4*)(X + (size_t)(r0 + row) * 256 + ch * 8);
            o = cvt8(gp[0], gp[1]);
        } else {
            for (int j = 0; j < 8; ++j) o[j] = (bf16_t)0.f;
        }
        *(bf16x8*)(sx + row * 256 + (ch ^ gray(row)) * 8) = o;
    }
    if (tid < ROWS) sseg[tid] = (r0 + tid < N) ? seg[r0 + tid] : -1;
    __syncthreads();

    f32x4 acc[3][2];

    // wm score MLP
    gemm256p(sx, wt_sw1_wm, acc, w, l);
    write_h(acc, b_sw1_wm, true, sh, w, l);
    __syncthreads();
    gemm_score(sh, wt_sw2_wm, b_sw2_wm, ssc, 0, w, l);
    __syncthreads();

    // ws score MLP
    gemm256p(sx, wt_sw1_ws, acc, w, l);
    write_h(acc, b_sw1_ws, true, sh, w, l);
    __syncthreads();
    gemm_score(sh, wt_sw2_ws, b_sw2_ws, ssc, 8, w, l);
    __syncthreads();

    // weights: cols 0-7 -> exp (softmax numerator); cols 8-15 -> sigmoid. 48*16=768 elems.
#pragma unroll
    for (int i = 0; i < 2; ++i) {
        const int idx = tid + i * 512;
        if (idx < ROWS * 16) {
            const float v = ssc[idx];
            ssc[idx] = ((idx & 15) < 8) ? __expf(v) : 1.f / (1.f + __expf(-v));
        }
    }
    __syncthreads();

    // wm value MLP
    gemm256p(sx, wt_vw1_wm, acc, w, l);
    write_h(acc, b_vw1_wm, true, sh, w, l);
    __syncthreads();
    gemm256p(sh, wt_vw2_wm, acc, w, l);
    __syncthreads();                           // all waves done reading sh
    write_h(acc, b_vw2_wm, false, sh, w, l);   // in-place
    __syncthreads();
    reduce_seg<true>(sh, ssc, sx, sseg, num_wm, den_wm, pmax, G);
    __syncthreads();

    // ws value MLP
    gemm256p(sx, wt_vw1_ws, acc, w, l);
    write_h(acc, b_vw1_ws, true, sh, w, l);
    __syncthreads();
    gemm256p(sh, wt_vw2_ws, acc, w, l);
    __syncthreads();
    write_h(acc, b_vw2_ws, false, sx, w, l);   // sx dead after wm-reduce's max pass
    __syncthreads();
    reduce_seg<false>(sx, ssc, sx, sseg, acc_ws, nullptr, nullptr, G);
}

__global__ __launch_bounds__(256, 2) void graph_kernel(
    const float* __restrict__ num_wm, const float* __restrict__ den_wm,
    const float* __restrict__ acc_ws, const unsigned* __restrict__ pmax,
    const bf16_t* __restrict__ wt_comb_wm, const bf16_t* __restrict__ wt_comb_ws,
    const bf16_t* __restrict__ wt_comb_mx, const bf16_t* __restrict__ wt_final,
    float* __restrict__ out, int G) {
    __shared__ __align__(16) bf16_t sa[16 * 256];
    __shared__ __align__(16) bf16_t sraw[16 * 1536];

    const int tid = threadIdx.x, w = tid >> 6, l = tid & 63;
    const int l15 = l & 15, hi = l >> 4;
    const int g0 = blockIdx.x * 16;

    for (int src = 0; src < 3; ++src) {
#pragma unroll
        for (int i = 0; i < 2; ++i) {
            const int cid = tid + i * 256;
            const int row = cid >> 5, ch = cid & 31;
            const int g = g0 + row;
            bf16x8 o;
            if (g < G) {
                if (src == 0) {
                    const float4* np = (const float4*)(num_wm + (size_t)g * 256 + ch * 8);
                    float4 v0 = np[0], v1 = np[1];
                    const float d = den_wm[(size_t)g * 8 + (ch >> 2)];
                    const float rd = (d > 0.f) ? 1.f / d : 0.f;
                    o[0] = (bf16_t)(v0.x * rd); o[1] = (bf16_t)(v0.y * rd);
                    o[2] = (bf16_t)(v0.z * rd); o[3] = (bf16_t)(v0.w * rd);
                    o[4] = (bf16_t)(v1.x * rd); o[5] = (bf16_t)(v1.y * rd);
                    o[6] = (bf16_t)(v1.z * rd); o[7] = (bf16_t)(v1.w * rd);
                } else if (src == 1) {
                    const float4* np = (const float4*)(acc_ws + (size_t)g * 256 + ch * 8);
                    o = cvt8(np[0], np[1]);
                } else {
                    const unsigned* mp = pmax + (size_t)g * 256 + ch * 8;
#pragma unroll
                    for (int j = 0; j < 8; ++j) o[j] = (bf16_t)dec_max(mp[j]);
                }
            } else {
                for (int j = 0; j < 8; ++j) o[j] = (bf16_t)0.f;
            }
            *(bf16x8*)(sa + row * 256 + (ch ^ gray(row)) * 8) = o;
        }
        __syncthreads();

        // comb GEMM [16,256]@[256,512]; weights k-major [k>>3][n 0..511][k&7]
        const bf16_t* Wt = (src == 0) ? wt_comb_wm : ((src == 1) ? wt_comb_ws : wt_comb_mx);
        bf16x8 a[8];
#pragma unroll
        for (int kt = 0; kt < 8; ++kt)
            a[kt] = *(const bf16x8*)(sa + l15 * 256 + ((kt * 4 + hi) ^ gray(l15)) * 8);
        f32x4 acc[8];
#pragma unroll
        for (int j = 0; j < 8; ++j) acc[j] = (f32x4){0.f, 0.f, 0.f, 0.f};
#pragma unroll
        for (int kt = 0; kt < 8; ++kt) {
            bf16x8 b[8];
#pragma unroll
            for (int j = 0; j < 8; ++j) {
                const int ncol = (w * 8 + j) * 16 + l15;
                b[j] = *(const bf16x8*)(Wt + ((size_t)(kt * 4 + hi) * 512 + ncol) * 8);
            }
#pragma unroll
            for (int j = 0; j < 8; ++j) acc[j] = MFMA16(a[kt], b[j], acc[j]);
        }
#pragma unroll
        for (int j = 0; j < 8; ++j) {
            const int col = src * 512 + (w * 8 + j) * 16 + l15;
#pragma unroll
            for (int r = 0; r < 4; ++r) {
                const int row = hi * 4 + r;
                const float v = fmaxf(acc[j][r], 0.f);
                sraw[row * 1536 + ((((col >> 3) ^ gray(row)) << 3) | (col & 7))] = (bf16_t)v;
            }
        }
        __syncthreads();
    }

    // final: [16,1536] @ [1536,512]; weights k-major
    f32x4 facc[8];
#pragma unroll
    for (int j = 0; j < 8; ++j) facc[j] = (f32x4){0.f, 0.f, 0.f, 0.f};
    for (int kt = 0; kt < 48; ++kt) {
        bf16x8 a = *(const bf16x8*)(sraw + l15 * 1536 + ((kt * 4 + hi) ^ gray(l15)) * 8);
#pragma unroll
        for (int j = 0; j < 8; ++j) {
            const int ncol = (w * 8 + j) * 16 + l15;
            bf16x8 b = *(const bf16x8*)(wt_final + ((size_t)(kt * 4 + hi) * 512 + ncol) * 8);
            facc[j] = MFMA16(a, b, facc[j]);
        }
    }
#pragma unroll
    for (int j = 0; j < 8; ++j) {
        const int col = (w * 8 + j) * 16 + l15;
#pragma unroll
        for (int r = 0; r < 4; ++r) {
            const int row = hi * 4 + r;
            if (g0 + row < G) out[(size_t)(g0 + row) * 512 + col] = facc[j][r];
        }
    }
}

// merged k-major prep: 12 weight tensors in one launch.
struct PrepTab {
    const float* src[12];
    bf16_t* dst[12];
    int K[12], Nn[12], Nout[12];
    int base[13];
};

__global__ void prep_all(PrepTab t) {
    const int idx = blockIdx.x * blockDim.x + threadIdx.x;
    if (idx >= t.base[12]) return;
    int i = 0;
#pragma unroll
    for (int s = 0; s < 12; ++s)
        if (idx >= t.base[s + 1]) i = s + 1;
    const int local = idx - t.base[i];
    const int j = local & 7;
    const int rest = local >> 3;
    const int n = rest % t.Nout[i];
    const int kc = rest / t.Nout[i];
    const int k = kc * 8 + j;
    const float v = (n < t.Nn[i]) ? t.src[i][(size_t)k * t.Nn[i] + n] : 0.f;
    t.dst[i][local] = (bf16_t)v;
}

extern "C" void kernel_launch(void* const* d_in, const int* in_sizes, int n_in,
                              void* d_out, int out_size, void* d_ws, size_t ws_size,
                              hipStream_t stream) {
    const float* X = (const float*)d_in[0];
    const int* seg = (const int*)d_in[1];   // int32: harness passes integers as int
    const int N = in_sizes[1];
    const int G = out_size / 512;

    float* num_wm = (float*)d_ws;                       // G*256 f32
    float* acc_ws = num_wm + (size_t)G * 256;           // G*256 f32
    float* den_wm = acc_ws + (size_t)G * 256;           // G*8   f32
    unsigned* pmax = (unsigned*)(den_wm + (size_t)G * 8);  // G*256 u32
    bf16_t* wt = (bf16_t*)(pmax + (size_t)G * 256);

    bf16_t* wt_sw1_wm = wt;                   // 256*256
    bf16_t* wt_sw2_wm = wt_sw1_wm + 65536;    // 256*16 (zero-padded)
    bf16_t* wt_vw1_wm = wt_sw2_wm + 4096;
    bf16_t* wt_vw2_wm = wt_vw1_wm + 65536;
    bf16_t* wt_sw1_ws = wt_vw2_wm + 65536;
    bf16_t* wt_sw2_ws = wt_sw1_ws + 65536;
    bf16_t* wt_vw1_ws = wt_sw2_ws + 4096;
    bf16_t* wt_vw2_ws = wt_vw1_ws + 65536;
    bf16_t* wt_comb_wm = wt_vw2_ws + 65536;   // 256*512
    bf16_t* wt_comb_ws = wt_comb_wm + 131072;
    bf16_t* wt_comb_mx = wt_comb_ws + 131072;
    bf16_t* wt_final = wt_comb_mx + 131072;   // 1536*512

    const size_t accum_bytes = ((size_t)G * 256 * 3 + (size_t)G * 8) * 4;
    hipMemsetAsync(d_ws, 0, accum_bytes, stream);

    struct TT { int srcIdx; bf16_t* dst; int K, Nn, Nout; };
    const TT tt[12] = {
        {3,  wt_sw1_wm, 256, 256, 256},  {5,  wt_sw2_wm, 256, 8,   16},
        {7,  wt_vw1_wm, 256, 256, 256},  {9,  wt_vw2_wm, 256, 256, 256},
        {12, wt_sw1_ws, 256, 256, 256},  {14, wt_sw2_ws, 256, 8,   16},
        {16, wt_vw1_ws, 256, 256, 256},  {18, wt_vw2_ws, 256, 256, 256},
        {11, wt_comb_wm, 256, 512, 512}, {20, wt_comb_ws, 256, 512, 512},
        {21, wt_comb_mx, 256, 512, 512}, {22, wt_final, 1536, 512, 512},
    };
    PrepTab pt;
    int base = 0;
    for (int i = 0; i < 12; ++i) {
        pt.src[i] = (const float*)d_in[tt[i].srcIdx];
        pt.dst[i] = tt[i].dst;
        pt.K[i] = tt[i].K; pt.Nn[i] = tt[i].Nn; pt.Nout[i] = tt[i].Nout;
        pt.base[i] = base;
        base += tt[i].K * tt[i].Nout;
    }
    pt.base[12] = base;
    prep_all<<<(base + 255) / 256, 256, 0, stream>>>(pt);

    const int nb = (N + ROWS - 1) / ROWS;
    node_kernel<<<nb, 512, 0, stream>>>(
        X, seg,
        wt_sw1_wm, wt_sw2_wm, wt_vw1_wm, wt_vw2_wm,
        wt_sw1_ws, wt_sw2_ws, wt_vw1_ws, wt_vw2_ws,
        (const float*)d_in[4], (const float*)d_in[6], (const float*)d_in[8], (const float*)d_in[10],
        (const float*)d_in[13], (const float*)d_in[15], (const float*)d_in[17], (const float*)d_in[19],
        num_wm, den_wm, acc_ws, pmax, N, G);

    const int gb = (G + 15) / 16;
    graph_kernel<<<gb, 256, 0, stream>>>(num_wm, den_wm, acc_ws, pmax,
                                         wt_comb_wm, wt_comb_ws, wt_comb_mx, wt_final,
                                         (float*)d_out, G);
}